// Round 5
// baseline (307.366 us; speedup 1.0000x reference)
//
#include <hip/hip_runtime.h>
#include <cstdint>
#include <cstddef>

// ---------------------------------------------------------------------------
// SpatialGRU 32x32, B=64, U=64, C=64. Persistent: 32 rows x 4 batch-tiles.
// R11 = R10 (split handoff th|zp|ei, 3 barriers/iter, GEMM2 n-split, parity
// double-buffered state, poll-overlapped GEMM1 split, XCD swizzle) + ONE
// change: SENTINEL POLLING. Only lane 0 of each consumer wave spins on its
// th dword; the other 63 lanes are exec-masked idle (zero memory traffic).
// After detect, all lanes finish their early-issued loads via validity-retry
// loops (~1 iteration). Cuts device-wide spin traffic ~64x — theory: the
// agent-atomic poll storm was queuing the MALL path and inflating the
// producer->consumer visibility latency from ~0.25us to ~5.7us/hop.
// Validity: every stored halfword has LSB|=1; harness ws poison 0xAA gives
// 0xAAAA halfwords (LSB=0) -> can never satisfy the check.
// ---------------------------------------------------------------------------

#define LDIM   32
#define NBT    4
#define BT     16
#define TPB    512
#define UNITS  64

typedef _Float16 f16;
typedef _Float16 f16x8 __attribute__((ext_vector_type(8)));
typedef float    f32x4 __attribute__((ext_vector_type(4)));

__global__ __launch_bounds__(TPB, 2) void spatial_gru_kernel(
    const float* __restrict__ x,     // (B, C, 32, 32)
    const float* __restrict__ W,     // (256, 448)
    const float* __restrict__ Urec,  // (192, 64)
    const float* __restrict__ bias,  // (512,)
    const float* __restrict__ Wij,   // (64, 64)
    float* __restrict__ out,         // (B, U)
    uint32_t* __restrict__ hbuf,     // slots of STR dwords: [th | zp | ei]
    const int SPLIT)
{
    // XCD-affinity swizzle: physical block p -> XCD p%8; 4 consecutive rows
    // per XCD so most vertical handoffs stay on-die. Bijective on [0,128).
    const int p    = blockIdx.x;
    const int xcd  = p & 7;
    const int slot = p >> 3;         // 0..15
    const int row  = xcd * 4 + (slot >> 2);
    const int bt   = slot & 3;
    const int b0   = bt * BT;
    const int t    = (int)threadIdx.x;
    const int u    = t & 63;
    const int g    = t >> 6;         // wave id 0..7
    const int l15  = t & 15;         // MFMA n-col / A-row lane
    const int lq   = (t & 63) >> 4;  // MFMA k-quad
    const int STR  = SPLIT ? 1536 : 512;

    // ---- LDS ----
    // qf  : GEMM1 A (f16) [b][k]: 0:64 hT | 64:128 hL | 128:192 hD |
    //       192:256 s(par0) | 256:320 s(par1)
    // rf  : GEMM2 A (f16) [b][0:192] = r*{hL,hT,hD}
    // qs32: fp32 state [b][c]: 0:64 hT | 64:128 hL0 | 128:192 hD0 |
    //       192:256 hL1 | 256:320 hD1   (hL/hD parity by j&1)
    // Gsz : z logits fp32 [b][0:256]; fallback mode only: [b][u]=zp,
    //       [b][64+u]=ei after the waves-0..3 softmax
    __shared__ __attribute__((aligned(16))) f16 qf[BT][328];
    __shared__ __attribute__((aligned(16))) f16 rf[BT][200];
    __shared__ float qs32[BT][324];
    __shared__ float Gsz [BT][260];

    // ---- GEMM1 weights resident (waves 0..6: 64 cols each) ----
    f16x8 wreg[4][8];
    float bias1[4] = {0.f, 0.f, 0.f, 0.f};
    if (g < 7) {
        const int nb = g * 64 + l15;
#pragma unroll
        for (int T = 0; T < 4; ++T) {
            bias1[T] = bias[nb + 16 * T];
#pragma unroll
            for (int s = 0; s < 8; ++s) {
                f16x8 v;
#pragma unroll
                for (int jj = 0; jj < 8; ++jj) {
                    int kk = s * 32 + lq * 8 + jj;
                    v[jj] = (f16)W[(size_t)kk * 448 + nb + 16 * T];
                }
                wreg[T][s] = v;
            }
        }
    }
    // ---- GEMM2 weights: waves 4..7 hold FULL K=256 for 16 n-cols each ----
    f16x8 wreg2[8];
    float bijE = 0.f;
    if (g >= 4) {
        const int nn = (g - 4) * 16 + l15;
        bijE = bias[448 + nn];
#pragma unroll
        for (int s = 0; s < 8; ++s) {
            f16x8 v;
#pragma unroll
            for (int jj = 0; jj < 8; ++jj) {
                int kk = s * 32 + lq * 8 + jj;
                float wv = (kk < 192) ? Urec[kk * 64 + nn] : Wij[(kk - 192) * 64 + nn];
                v[jj] = (f16)wv;
            }
            wreg2[s] = v;
        }
    }

    // ---- zero init: all qs32 state, qf hT/hL/hD (0:192) ----
    for (int idx = t; idx < BT * 324; idx += TPB)
        ((float*)qs32)[idx] = 0.f;
    for (int idx = t; idx < 192 * BT; idx += TPB) {
        int b = idx & 15, k = idx >> 4;
        qf[b][k] = (f16)0.f;
    }

    // x: this thread handles channel u, batches b0+g and b0+g+8
    const size_t xb0 = (size_t)(b0 + g) * 65536 + (size_t)u * 1024 + (size_t)row * 32;
    const size_t xb1 = xb0 + (size_t)8 * 65536;
    {   // stage x(j=0) into parity-0 s slot
        float x0 = x[xb0], x1 = x[xb1];
        qf[g][192 + u]     = (f16)x0;
        qf[g + 8][192 + u] = (f16)x1;
    }

    for (int j = 0; j < LDIM; ++j) {
        const int par  = j & 1;
        const int scur = 192 + par * 64;
        const int snxt = 192 + (par ^ 1) * 64;
        const int hlc  = 64 + par * 128, hdc = 128 + par * 128;
        const int hln  = 64 + (par ^ 1) * 128, hdn = 128 + (par ^ 1) * 128;

        __syncthreads();   // s1 — prev-tail writes (h, rotations, x) visible

        // ---- [A] issue own-dword poll loads (fly during [C-pre]) ----
        uint32_t wT = 0, wZ = 0, wE = 0;
        const uint32_t* sp = hbuf;
        if (row > 0) {
            sp = hbuf + (size_t)(((row - 1) * LDIM + j) * NBT + bt) * STR + (g << 6) + u;
            wT = __hip_atomic_load(sp, __ATOMIC_RELAXED, __HIP_MEMORY_SCOPE_AGENT);
            if (SPLIT) {
                wZ = __hip_atomic_load(sp + 512,  __ATOMIC_RELAXED, __HIP_MEMORY_SCOPE_AGENT);
                wE = __hip_atomic_load(sp + 1024, __ATOMIC_RELAXED, __HIP_MEMORY_SCOPE_AGENT);
            }
        }
        float nx0 = 0.f, nx1 = 0.f;
        if (j < LDIM - 1) { nx0 = x[xb0 + j + 1]; nx1 = x[xb1 + j + 1]; }

        // ---- [C-pre] GEMM1 k=64:256 (waves 0..6; hL/hD/s all local) ----
        f32x4 acc[4];
        if (g < 7) {
#pragma unroll
            for (int T = 0; T < 4; ++T)
                acc[T] = (f32x4){bias1[T], bias1[T], bias1[T], bias1[T]};
#pragma unroll
            for (int s = 2; s < 8; ++s) {
                const f16* ap = (s < 6) ? &qf[l15][s * 32 + lq * 8]
                                        : &qf[l15][scur + (s - 6) * 32 + lq * 8];
                f16x8 a = *(const f16x8*)ap;
#pragma unroll
                for (int T = 0; T < 4; ++T)
                    acc[T] = __builtin_amdgcn_mfma_f32_16x16x32_f16(a, wreg[T][s], acc[T], 0, 0, 0);
            }
        }

        // ---- [A'] SENTINEL poll (lane 0 of each wave spins; other 63 lanes
        //      exec-masked idle -> ~64x less spin traffic), then per-lane
        //      validity-retry completion; reconstruct h; stage hT ----
        {
            float ht0 = 0.f, ht1 = 0.f;
            f16 hf0 = (f16)0.f, hf1 = (f16)0.f;
            if (row > 0) {
                // sentinel: lane 0 spins on its own th dword (th gates the edge)
                if ((t & 63) == 0) {
                    uint32_t s0 = wT;
                    while ((s0 & 0x00010001u) != 0x00010001u) {
                        __builtin_amdgcn_s_sleep(1);
                        s0 = __hip_atomic_load(sp, __ATOMIC_RELAXED, __HIP_MEMORY_SCOPE_AGENT);
                    }
                }
                // wave reconverged: producer has (mostly) stored; finish loads
                while ((wT & 0x00010001u) != 0x00010001u) {
                    __builtin_amdgcn_s_sleep(1);
                    wT = __hip_atomic_load(sp, __ATOMIC_RELAXED, __HIP_MEMORY_SCOPE_AGENT);
                }
                if (SPLIT) {
                    while ((wZ & 0x00010001u) != 0x00010001u) {
                        __builtin_amdgcn_s_sleep(1);
                        wZ = __hip_atomic_load(sp + 512, __ATOMIC_RELAXED, __HIP_MEMORY_SCOPE_AGENT);
                    }
                    while ((wE & 0x00010001u) != 0x00010001u) {
                        __builtin_amdgcn_s_sleep(1);
                        wE = __hip_atomic_load(sp + 1024, __ATOMIC_RELAXED, __HIP_MEMORY_SCOPE_AGENT);
                    }
                    f16 th0 = __builtin_bit_cast(f16, (uint16_t)(wT & 0xFFFFu));
                    f16 th1 = __builtin_bit_cast(f16, (uint16_t)(wT >> 16));
                    f16 zp0 = __builtin_bit_cast(f16, (uint16_t)(wZ & 0xFFFFu));
                    f16 zp1 = __builtin_bit_cast(f16, (uint16_t)(wZ >> 16));
                    f16 ei0 = __builtin_bit_cast(f16, (uint16_t)(wE & 0xFFFFu));
                    f16 ei1 = __builtin_bit_cast(f16, (uint16_t)(wE >> 16));
                    ht0 = (float)zp0 + (float)ei0 * (float)th0;
                    ht1 = (float)zp1 + (float)ei1 * (float)th1;
                    hf0 = (f16)ht0;
                    hf1 = (f16)ht1;
                } else {
                    hf0 = __builtin_bit_cast(f16, (uint16_t)(wT & 0xFFFFu));
                    hf1 = __builtin_bit_cast(f16, (uint16_t)(wT >> 16));
                    ht0 = (float)hf0;
                    ht1 = (float)hf1;
                }
            }
            qs32[g][u]     = ht0;  qf[g][u]     = hf0;
            qs32[g + 8][u] = ht1;  qf[g + 8][u] = hf1;
        }
        __syncthreads();   // s1b — hT staged visible

        // ---- [C-post] GEMM1 k=0:64 (waves 0..6) + sigmoid/z dumps ----
        if (g < 7) {
            {
                f16x8 a0 = *(const f16x8*)&qf[l15][lq * 8];
                f16x8 a1 = *(const f16x8*)&qf[l15][32 + lq * 8];
#pragma unroll
                for (int T = 0; T < 4; ++T)
                    acc[T] = __builtin_amdgcn_mfma_f32_16x16x32_f16(a0, wreg[T][0], acc[T], 0, 0, 0);
#pragma unroll
                for (int T = 0; T < 4; ++T)
                    acc[T] = __builtin_amdgcn_mfma_f32_16x16x32_f16(a1, wreg[T][1], acc[T], 0, 0, 0);
            }
            if (g < 3) {
                // g=0: r*hL ; g=1: r*hT ; g=2: r*hD   (parity-cur states)
                const int colbase = (g == 0) ? hlc : (g == 1) ? 0 : hdc;
#pragma unroll
                for (int T = 0; T < 4; ++T)
#pragma unroll
                    for (int r = 0; r < 4; ++r) {
                        float rr = 1.f / (1.f + __expf(-acc[T][r]));
                        int b = lq * 4 + r;
                        float hv = qs32[b][colbase + T * 16 + l15];
                        rf[b][g * 64 + T * 16 + l15] = (f16)(rr * hv);
                    }
            } else {
                const int zb = (g - 3) * 64;
#pragma unroll
                for (int T = 0; T < 4; ++T)
#pragma unroll
                    for (int r = 0; r < 4; ++r)
                        Gsz[lq * 4 + r][zb + T * 16 + l15] = acc[T][r];
            }
        }
        __syncthreads();   // s2 — rf + Gsz + (parity-cur states) stable

        // ---- [E'] barrier-free tail span ----
        const size_t curbase = (size_t)((row * LDIM + j) * NBT + bt) * STR;
        uint16_t* hp16 = (uint16_t*)(hbuf + curbase);
        float thv[4] = {0.f, 0.f, 0.f, 0.f};

        if (g >= 4) {
            // full-K GEMM2 (8 MFMA, 2 interleaved acc chains)
            f32x4 aA = (f32x4){0.f, 0.f, 0.f, 0.f};
            f32x4 aB = (f32x4){0.f, 0.f, 0.f, 0.f};
#pragma unroll
            for (int s = 0; s < 8; s += 2) {
                const f16* apA = (s < 6) ? &rf[l15][s * 32 + lq * 8]
                                         : &qf[l15][scur + (s - 6) * 32 + lq * 8];
                f16x8 a = *(const f16x8*)apA;
                aA = __builtin_amdgcn_mfma_f32_16x16x32_f16(a, wreg2[s], aA, 0, 0, 0);
                const f16* apB = (s + 1 < 6) ? &rf[l15][(s + 1) * 32 + lq * 8]
                                             : &qf[l15][scur + (s + 1 - 6) * 32 + lq * 8];
                f16x8 b_ = *(const f16x8*)apB;
                aB = __builtin_amdgcn_mfma_f32_16x16x32_f16(b_, wreg2[s + 1], aB, 0, 0, 0);
            }
            const int n = (g - 4) * 16 + l15;
            // th: compute + (split) store IMMEDIATELY — this gates row+1
#pragma unroll
            for (int rr = 0; rr < 4; ++rr) {
                const int b = lq * 4 + rr;
                float hh = bijE + aA[rr] + aB[rr];
                float e2 = __expf(2.f * hh);
                thv[rr] = 1.f - 2.f / (e2 + 1.f);        // tanh
                if (SPLIT) {
                    uint16_t th16 = (uint16_t)(__builtin_bit_cast(uint16_t, (f16)thv[rr]) | 1u);
                    __hip_atomic_store(hp16 + ((((b & 7) << 6) + n) << 1) + (b >> 3),
                                       th16, __ATOMIC_RELAXED, __HIP_MEMORY_SCOPE_AGENT);
                }
            }
            if (SPLIT) {
                // OFF-CHAIN: own softmax (pre-s2 data only) -> local h for
                // rotation + out. Duplicated with waves 0..3 by design.
#pragma unroll
                for (int rr = 0; rr < 4; ++rr) {
                    const int b = lq * 4 + rr;
                    float zi = Gsz[b][n],       zl = Gsz[b][64 + n];
                    float zt = Gsz[b][128 + n], zd = Gsz[b][192 + n];
                    float hT = qs32[b][n], hL = qs32[b][hlc + n], hD = qs32[b][hdc + n];
                    float mx = fmaxf(fmaxf(zi, zl), fmaxf(zt, zd));
                    float ei = __expf(zi - mx), el = __expf(zl - mx);
                    float et = __expf(zt - mx), ed = __expf(zd - mx);
                    float inv = 1.f / (ei + el + et + ed);
                    float h = (el * hL + et * hT + ed * hD + ei * thv[rr]) * inv;
                    qs32[b][hln + n] = h;          // rotation hL(next) <- h
                    qf[b][64 + n]    = (f16)h;
                    if (row == LDIM - 1 && j == LDIM - 1)
                        out[(size_t)(b0 + b) * UNITS + n] = h;
                }
            }
        } else {
            // waves 0..3: softmax partials; split -> straight to hbuf;
            // fallback -> Gsz in place. Plus hD<-hT parity rotation.
#pragma unroll
            for (int i = 0; i < 4; ++i) {
                const int b = g * 4 + i;
                float zi = Gsz[b][u],       zl = Gsz[b][64 + u];
                float zt = Gsz[b][128 + u], zd = Gsz[b][192 + u];
                float hT = qs32[b][u], hL = qs32[b][hlc + u], hD = qs32[b][hdc + u];
                float mx = fmaxf(fmaxf(zi, zl), fmaxf(zt, zd));
                float ei = __expf(zi - mx), el = __expf(zl - mx);
                float et = __expf(zt - mx), ed = __expf(zd - mx);
                float inv = 1.f / (ei + el + et + ed);
                float zp  = (el * hL + et * hT + ed * hD) * inv;
                float eiv = ei * inv;
                if (SPLIT) {
                    uint16_t zp16 = (uint16_t)(__builtin_bit_cast(uint16_t, (f16)zp)  | 1u);
                    uint16_t ei16 = (uint16_t)(__builtin_bit_cast(uint16_t, (f16)eiv) | 1u);
                    const int dw = ((b & 7) << 6) + u;
                    __hip_atomic_store(hp16 + ((512  + dw) << 1) + (b >> 3),
                                       zp16, __ATOMIC_RELAXED, __HIP_MEMORY_SCOPE_AGENT);
                    __hip_atomic_store(hp16 + ((1024 + dw) << 1) + (b >> 3),
                                       ei16, __ATOMIC_RELAXED, __HIP_MEMORY_SCOPE_AGENT);
                } else {
                    Gsz[b][u]      = zp;
                    Gsz[b][64 + u] = eiv;
                }
                // rotation: hD(next parity) <- hT(cur)
                qs32[b][hdn + u] = hT;
                qf[b][128 + u]   = qf[b][u];
            }
        }
        // stage next x into parity-next s slot (thread-own; read next iter)
        qf[g][snxt + u]     = (f16)nx0;
        qf[g + 8][snxt + u] = (f16)nx1;

        if (!SPLIT) {
            __syncthreads();   // sF — zp/ei in Gsz visible (fallback only)
            if (g >= 4) {
                const int n = (g - 4) * 16 + l15;
#pragma unroll
                for (int rr = 0; rr < 4; ++rr) {
                    const int b = lq * 4 + rr;
                    float h = Gsz[b][n] + Gsz[b][64 + n] * thv[rr];
                    uint16_t h16 = (uint16_t)(__builtin_bit_cast(uint16_t, (f16)h) | 1u);
                    __hip_atomic_store(hp16 + ((((b & 7) << 6) + n) << 1) + (b >> 3),
                                       h16, __ATOMIC_RELAXED, __HIP_MEMORY_SCOPE_AGENT);
                    qs32[b][hln + n] = h;
                    qf[b][64 + n]    = (f16)h;
                    if (row == LDIM - 1 && j == LDIM - 1)
                        out[(size_t)(b0 + b) * UNITS + n] = h;
                }
            }
        }
        // next s1 covers cross-wave visibility of all tail writes
    }
}

extern "C" void kernel_launch(void* const* d_in, const int* in_sizes, int n_in,
                              void* d_out, int out_size, void* d_ws, size_t ws_size,
                              hipStream_t stream) {
    const float* x    = (const float*)d_in[0];
    const float* W    = (const float*)d_in[1];
    const float* Urec = (const float*)d_in[2];
    const float* bias = (const float*)d_in[3];
    const float* Wij  = (const float*)d_in[4];
    float* out = (float*)d_out;

    // Split handoff needs 32*32*4 slots x 1536 dwords = 24 MB of workspace.
    // Harness re-poisons ws with 0xAA each launch; 0xAAAA halfwords always
    // fail the LSB validity test in either mode.
    const size_t need = (size_t)LDIM * LDIM * NBT * 1536 * 4;
    const int split = (ws_size >= need) ? 1 : 0;
    uint32_t* hbuf = (uint32_t*)d_ws;

    spatial_gru_kernel<<<LDIM * NBT, TPB, 0, stream>>>(
        x, W, Urec, bias, Wij, out, hbuf, split);
}

// Round 6
// 290.608 us; speedup vs baseline: 1.0577x; 1.0577x over previous
//
#include <hip/hip_runtime.h>
#include <cstdint>
#include <cstddef>

// ---------------------------------------------------------------------------
// SpatialGRU 32x32, B=64, U=64, C=64. R12: STAIRCASE BLOCKS.
// 8 row-groups x 16 batch-tiles (BT=4) = 128 blocks. Each block owns 4 rows,
// processed staggered: cell k handles col s-k at step s (cells independent
// within a step). The 4 cells batch-fuse into ONE M=16 GEMM pipeline, so the
// per-step MFMA structure is identical to before; only staging differs:
//  - hT for cells 1..3 comes from cell-1's h via LDS rotation (parity-buffered
//    hT/hL/hD/x) -> 3 of 4 vertical handoffs leave global memory entirely.
//  - only cell3 stores to hbuf (128 dw/slot); only cell0 polls (128 threads).
//  - invalid staircase-edge cells compute on zeros (finite) and their state
//    writes are gated to 0, so validity propagates exactly.
// Serial path: 35 steps + 7 inter-block lags (was 63 steps + 31 lags).
// Keeps: 3-barrier skeleton, poll-overlapped GEMM1 split (hT chunks last),
// GEMM2 n-split fused tail (full K=256 on waves 4..7).
// Validity: stored halfwords have LSB|=1; ws poison 0xAA fails the check.
// hbuf: (7 grp-edges, 32 cols, 16 bt) slots x 128 dwords = 1.83 MB.
// ---------------------------------------------------------------------------

#define LDIM   32
#define GRPS   8
#define RPB    4
#define NBT    16
#define BT     4
#define TPB    512
#define UNITS  64
#define STEPS  (LDIM + RPB - 1)   // 35

typedef _Float16 f16;
typedef _Float16 f16x8 __attribute__((ext_vector_type(8)));
typedef float    f32x4 __attribute__((ext_vector_type(4)));

__global__ __launch_bounds__(TPB, 2) void spatial_gru_kernel(
    const float* __restrict__ x,     // (B, C, 32, 32)
    const float* __restrict__ W,     // (256, 448)
    const float* __restrict__ Urec,  // (192, 64)
    const float* __restrict__ bias,  // (512,)
    const float* __restrict__ Wij,   // (64, 64)
    float* __restrict__ out,         // (B, U)
    uint32_t* __restrict__ hbuf)
{
    const int p   = blockIdx.x;
    const int grp = p >> 4;          // row group 0..7 (rows grp*4 .. grp*4+3)
    const int bt  = p & 15;          // batch tile 0..15 (batches bt*4..bt*4+3)
    const int t   = (int)threadIdx.x;
    const int u   = t & 63;
    const int g   = t >> 6;          // wave 0..7
    const int l15 = t & 15;          // MFMA A-row lane (M-row = cell*4+batch)
    const int lq  = (t & 63) >> 4;   // MFMA k-quad

    // ---- LDS ----
    // M-row m = cell*4 + batch_in_tile. All per-row, parity double-buffered.
    // qf  (f16): [m][ hT0 0 | hT1 64 | hL0 128 | hL1 192 | hD0 256 | hD1 320
    //               | x0 384 | x1 448 ]
    // qs32(f32): [m][ hT0 0 | hT1 64 | hL0 128 | hL1 192 | hD0 256 | hD1 320 ]
    // rf  (f16): [m][0:192] = r*{hL,hT,hD} (cur step, no parity needed)
    // Gsz (f32): [m][0:256] z logits
    __shared__ __attribute__((aligned(16))) f16 qf[16][520];
    __shared__ __attribute__((aligned(16))) f16 rf[16][200];
    __shared__ float qs32[16][388];
    __shared__ float Gsz [16][260];

    // ---- GEMM1 weights resident (waves 0..6: 64 n-cols each) ----
    f16x8 wreg[4][8];
    float bias1[4] = {0.f, 0.f, 0.f, 0.f};
    if (g < 7) {
        const int nb = g * 64 + l15;
#pragma unroll
        for (int T = 0; T < 4; ++T) {
            bias1[T] = bias[nb + 16 * T];
#pragma unroll
            for (int s = 0; s < 8; ++s) {
                f16x8 v;
#pragma unroll
                for (int jj = 0; jj < 8; ++jj) {
                    int kk = s * 32 + lq * 8 + jj;
                    v[jj] = (f16)W[(size_t)kk * 448 + nb + 16 * T];
                }
                wreg[T][s] = v;
            }
        }
    }
    // ---- GEMM2 weights: waves 4..7 hold FULL K=256 for 16 n-cols each ----
    f16x8 wreg2[8];
    float bijE = 0.f;
    if (g >= 4) {
        const int nn = (g - 4) * 16 + l15;
        bijE = bias[448 + nn];
#pragma unroll
        for (int s = 0; s < 8; ++s) {
            f16x8 v;
#pragma unroll
            for (int jj = 0; jj < 8; ++jj) {
                int kk = s * 32 + lq * 8 + jj;
                float wv = (kk < 192) ? Urec[kk * 64 + nn] : Wij[(kk - 192) * 64 + nn];
                v[jj] = (f16)wv;
            }
            wreg2[s] = v;
        }
    }

    // ---- zero init all states (both parities) ----
    for (int idx = t; idx < 16 * 388; idx += TPB) {
        int b = idx & 15, k = idx >> 4;
        qs32[b][k] = 0.f;
    }
    for (int idx = t; idx < 16 * 384; idx += TPB) {
        int b = idx & 15, k = idx >> 4;
        qf[b][k] = (f16)0.f;
    }

    // x: thread (g,u) loads chan u for M-rows m0=2g, m1=2g+1
    const int m0 = g * 2, m1 = g * 2 + 1;
    const size_t xb0 = ((size_t)(bt * BT + (m0 & 3)) << 16) + ((size_t)u << 10)
                     + ((size_t)(grp * RPB + (m0 >> 2)) << 5);
    const size_t xb1 = ((size_t)(bt * BT + (m1 & 3)) << 16) + ((size_t)u << 10)
                     + ((size_t)(grp * RPB + (m1 >> 2)) << 5);
    // stage x for step 0 (col = -cell: only cell0 valid) into parity-0 slot
    qf[m0][384 + u] = (f16)(((m0 >> 2) == 0) ? x[xb0] : 0.f);
    qf[m1][384 + u] = (f16)(((m1 >> 2) == 0) ? x[xb1] : 0.f);

    for (int s = 0; s < STEPS; ++s) {
        const int par = s & 1;
        const int fhT = par * 64,        nhT = (par ^ 1) * 64;
        const int fhL = 128 + par * 64,  nhL = 128 + (par ^ 1) * 64;
        const int fhD = 256 + par * 64,  nhD = 256 + (par ^ 1) * 64;
        const int fx  = 384 + par * 64,  nx  = 384 + (par ^ 1) * 64;
        const int shT = par * 64,        tnT = (par ^ 1) * 64;
        const int shL = 128 + par * 64,  tnL = 128 + (par ^ 1) * 64;
        const int shD = 256 + par * 64,  tnD = 256 + (par ^ 1) * 64;

        __syncthreads();   // s1 — prev-step tail (rotations, h, x) visible

        // ---- [A] issue poll (waves 0,1 only; own dword; flies over C-pre) ----
        uint32_t wv = 0;
        const uint32_t* sp = hbuf;
        const bool polling = (grp > 0) && (s < LDIM) && (t < 128);
        if (polling) {
            sp = hbuf + (((size_t)((grp - 1) * LDIM + s) * NBT + bt) << 7) + t;
            wv = __hip_atomic_load(sp, __ATOMIC_RELAXED, __HIP_MEMORY_SCOPE_AGENT);
        }
        // x prefetch: per row, next col = s+1-cell
        float nxv0 = 0.f, nxv1 = 0.f;
        {
            const int col0 = s + 1 - (m0 >> 2);
            const int col1 = s + 1 - (m1 >> 2);
            if ((unsigned)col0 < (unsigned)LDIM) nxv0 = x[xb0 + col0];
            if ((unsigned)col1 < (unsigned)LDIM) nxv1 = x[xb1 + col1];
        }

        // ---- [C-pre] GEMM1 k=64:256 (hL, hD, x — all local/rotated) ----
        f32x4 acc[4];
        if (g < 7) {
#pragma unroll
            for (int T = 0; T < 4; ++T)
                acc[T] = (f32x4){bias1[T], bias1[T], bias1[T], bias1[T]};
#pragma unroll
            for (int sc = 2; sc < 8; ++sc) {
                const int base = (sc < 4 ? fhL : sc < 6 ? fhD : fx) + (sc & 1) * 32;
                f16x8 a = *(const f16x8*)&qf[l15][base + lq * 8];
#pragma unroll
                for (int T = 0; T < 4; ++T)
                    acc[T] = __builtin_amdgcn_mfma_f32_16x16x32_f16(a, wreg[T][sc], acc[T], 0, 0, 0);
            }
        }

        // ---- [A'] finish poll; stage cell0 hT (rows 0..3, cur parity) ----
        if (polling) {
            while ((wv & 0x00010001u) != 0x00010001u) {
                __builtin_amdgcn_s_sleep(1);
                wv = __hip_atomic_load(sp, __ATOMIC_RELAXED, __HIP_MEMORY_SCOPE_AGENT);
            }
            const int uu = t >> 1, bp = (t & 1) * 2;
            f16 lo = __builtin_bit_cast(f16, (uint16_t)(wv & 0xFFFFu));
            f16 hi = __builtin_bit_cast(f16, (uint16_t)(wv >> 16));
            qs32[bp][shT + uu]     = (float)lo;  qf[bp][fhT + uu]     = lo;
            qs32[bp + 1][shT + uu] = (float)hi;  qf[bp + 1][fhT + uu] = hi;
        }
        __syncthreads();   // s1b — hT staged visible

        // ---- [C-post] GEMM1 k=0:64 (hT) + sigmoid->rf / z->Gsz ----
        if (g < 7) {
            {
                f16x8 a0 = *(const f16x8*)&qf[l15][fhT + lq * 8];
                f16x8 a1 = *(const f16x8*)&qf[l15][fhT + 32 + lq * 8];
#pragma unroll
                for (int T = 0; T < 4; ++T)
                    acc[T] = __builtin_amdgcn_mfma_f32_16x16x32_f16(a0, wreg[T][0], acc[T], 0, 0, 0);
#pragma unroll
                for (int T = 0; T < 4; ++T)
                    acc[T] = __builtin_amdgcn_mfma_f32_16x16x32_f16(a1, wreg[T][1], acc[T], 0, 0, 0);
            }
            if (g < 3) {
                // g=0: r_l*hL ; g=1: r_t*hT ; g=2: r_d*hD  (cur-parity states)
                const int colbase = (g == 0) ? shL : (g == 1) ? shT : shD;
#pragma unroll
                for (int T = 0; T < 4; ++T)
#pragma unroll
                    for (int r = 0; r < 4; ++r) {
                        float rr = 1.f / (1.f + __expf(-acc[T][r]));
                        int b = lq * 4 + r;
                        rf[b][g * 64 + T * 16 + l15] =
                            (f16)(rr * qs32[b][colbase + T * 16 + l15]);
                    }
            } else {
                const int zb = (g - 3) * 64;
#pragma unroll
                for (int T = 0; T < 4; ++T)
#pragma unroll
                    for (int r = 0; r < 4; ++r)
                        Gsz[lq * 4 + r][zb + T * 16 + l15] = acc[T][r];
            }
        }
        __syncthreads();   // s2 — rf + Gsz ready

        // ---- [E'] waves 4..7: full-K GEMM2 + fused tanh/softmax/combine +
        //      rotations (hL next, hT next for cell+1) + cell3 handoff.
        //      waves 0..3: hD(next) <- hT(cur) rotation. ----
        if (g >= 4) {
            f32x4 aA = (f32x4){0.f, 0.f, 0.f, 0.f};
            f32x4 aB = (f32x4){0.f, 0.f, 0.f, 0.f};
            {
                f16x8 a;
                a = *(const f16x8*)&rf[l15][  0 + lq * 8]; aA = __builtin_amdgcn_mfma_f32_16x16x32_f16(a, wreg2[0], aA, 0, 0, 0);
                a = *(const f16x8*)&rf[l15][ 32 + lq * 8]; aB = __builtin_amdgcn_mfma_f32_16x16x32_f16(a, wreg2[1], aB, 0, 0, 0);
                a = *(const f16x8*)&rf[l15][ 64 + lq * 8]; aA = __builtin_amdgcn_mfma_f32_16x16x32_f16(a, wreg2[2], aA, 0, 0, 0);
                a = *(const f16x8*)&rf[l15][ 96 + lq * 8]; aB = __builtin_amdgcn_mfma_f32_16x16x32_f16(a, wreg2[3], aB, 0, 0, 0);
                a = *(const f16x8*)&rf[l15][128 + lq * 8]; aA = __builtin_amdgcn_mfma_f32_16x16x32_f16(a, wreg2[4], aA, 0, 0, 0);
                a = *(const f16x8*)&rf[l15][160 + lq * 8]; aB = __builtin_amdgcn_mfma_f32_16x16x32_f16(a, wreg2[5], aB, 0, 0, 0);
                a = *(const f16x8*)&qf[l15][fx + lq * 8];      aA = __builtin_amdgcn_mfma_f32_16x16x32_f16(a, wreg2[6], aA, 0, 0, 0);
                a = *(const f16x8*)&qf[l15][fx + 32 + lq * 8]; aB = __builtin_amdgcn_mfma_f32_16x16x32_f16(a, wreg2[7], aB, 0, 0, 0);
            }
            const int n = (g - 4) * 16 + l15;
            uint32_t h16[4];
#pragma unroll
            for (int rr = 0; rr < 4; ++rr) {
                const int b = lq * 4 + rr;
                const int c = b >> 2;
                const int col = s - c;
                const bool valid = (unsigned)col < (unsigned)LDIM;
                float hh = bijE + aA[rr] + aB[rr];
                float e2 = __expf(2.f * hh);
                float th = 1.f - 2.f / (e2 + 1.f);          // tanh
                float zi = Gsz[b][n],        zl = Gsz[b][64 + n];
                float zt = Gsz[b][128 + n],  zd = Gsz[b][192 + n];
                float hT = qs32[b][shT + n], hL = qs32[b][shL + n], hD = qs32[b][shD + n];
                float mx = fmaxf(fmaxf(zi, zl), fmaxf(zt, zd));
                float ei = __expf(zi - mx), el = __expf(zl - mx);
                float et = __expf(zt - mx), ed = __expf(zd - mx);
                float inv = 1.f / (ei + el + et + ed);
                float h  = (el * hL + et * hT + ed * hD + ei * th) * inv;
                float hs = valid ? h : 0.f;                 // gate edge cells
                f16 hf = (f16)hs;
                h16[rr] = (uint32_t)(__builtin_bit_cast(uint16_t, hf) | 1u);
                qs32[b][tnL + n] = hs;                      // hL(next) <- h
                qf[b][nhL + n]   = hf;
                if (b < 12) {                               // hT(next, cell+1)
                    qs32[b + 4][tnT + n] = hs;
                    qf[b + 4][nhT + n]   = hf;
                }
                if (b >= 12 && grp == GRPS - 1 && col == LDIM - 1)
                    out[(size_t)(bt * BT + (b & 3)) * UNITS + n] = h;
            }
            // cell3 handoff: lanes lq==3 hold rows 12..15 -> 2 packed dwords
            if (lq == 3 && grp < GRPS - 1 && (unsigned)(s - 3) < (unsigned)LDIM) {
                uint32_t* hp = hbuf + (((size_t)(grp * LDIM + (s - 3)) * NBT + bt) << 7);
                __hip_atomic_store(hp + n * 2,     h16[0] | (h16[1] << 16),
                                   __ATOMIC_RELAXED, __HIP_MEMORY_SCOPE_AGENT);
                __hip_atomic_store(hp + n * 2 + 1, h16[2] | (h16[3] << 16),
                                   __ATOMIC_RELAXED, __HIP_MEMORY_SCOPE_AGENT);
            }
        } else {
            // waves 0..3: hD(next) <- hT(cur) for all 16 rows
#pragma unroll
            for (int i = 0; i < 4; ++i) {
                const int b = g + 4 * i;
                qs32[b][tnD + u] = qs32[b][shT + u];
                qf[b][nhD + u]   = qf[b][fhT + u];
            }
        }
        // stage next x (thread-own rows, next parity)
        qf[m0][nx + u] = (f16)nxv0;
        qf[m1][nx + u] = (f16)nxv1;
        // next s1 covers cross-wave visibility of all tail writes
    }
}

extern "C" void kernel_launch(void* const* d_in, const int* in_sizes, int n_in,
                              void* d_out, int out_size, void* d_ws, size_t ws_size,
                              hipStream_t stream) {
    const float* x    = (const float*)d_in[0];
    const float* W    = (const float*)d_in[1];
    const float* Urec = (const float*)d_in[2];
    const float* bias = (const float*)d_in[3];
    const float* Wij  = (const float*)d_in[4];
    float* out = (float*)d_out;

    // hbuf: (7 edges * 32 cols * 16 bt) slots x 128 dwords = 1.83 MB << ws.
    // Harness re-poisons ws with 0xAA each launch; 0xAAAA halfwords fail the
    // per-half LSB validity test.
    uint32_t* hbuf = (uint32_t*)d_ws;

    spatial_gru_kernel<<<GRPS * NBT, TPB, 0, stream>>>(
        x, W, Urec, bias, Wij, out, hbuf);
}